// Round 13
// baseline (164.973 us; speedup 1.0000x reference)
//
#include <hip/hip_runtime.h>
#include <hip/hip_bf16.h>
#include <stdint.h>
#include <stddef.h>

#define NB 32
#define NN 8192
#define NH 512
#define NE 10
#define HEPS 1e-5f
#define HSLOPE 0.2f

typedef short short8 __attribute__((ext_vector_type(8)));
typedef float f32x4 __attribute__((ext_vector_type(4)));
typedef float f32x16 __attribute__((ext_vector_type(16)));

static __device__ __forceinline__ unsigned short sbf(float a){
  __hip_bfloat16 t = __float2bfloat16(a);
  return *reinterpret_cast<unsigned short*>(&t);
}
static __device__ __forceinline__ unsigned pkbf(float a, float b){
  float2 f2; f2.x = a; f2.y = b;
  __hip_bfloat162 t = __float22bfloat162_rn(f2);
  return *reinterpret_cast<unsigned*>(&t);
}

// ---------------------------------------------------------------------------
// Prep: W2 [E][512][256] f32 -> bf16 image for 32x32x16 fragments (as R10).
// [e][t(32)][col(256)][kh(2)][kk(8)]: a wave's 32-col frag at k-step t is
// one coalesced 16B/lane load.
// ---------------------------------------------------------------------------
__global__ __launch_bounds__(256) void prep_w2(const float* __restrict__ W2,
                                               unsigned short* __restrict__ ws){
  int idx = blockIdx.x * 256 + threadIdx.x;
  int col = idx & 255;
  int k   = (idx >> 8) & 511;
  int e   = idx >> 17;
  int t = k >> 4, kh = (k >> 3) & 1, kk = k & 7;
  ws[(((size_t)(e * 32 + t)) << 12) + (col << 4) + (kh << 3) + kk] = sbf(W2[idx]);
}

// ---------------------------------------------------------------------------
// Main (R13): BM=64, 512 thr (8 waves), 64KB LDS -> 2 blocks/CU = 16 waves/CU
// (same occupancy as R10) but B L2 traffic and B-load instructions HALVED
// (amortized over 2x rows). 32x32x16 swapped pipeline throughout.
//  L1  : wave w computes feature-cols [64w,64w+64) x 64 rows: 2mi x 2ni MFMA;
//        LN1 stats lane-local + shfl(32) + stf[64][8][2] (aliases As);
//        normalize+lrelu -> packed uint2 frag-major As (64 frags x 1KB).
//  GEMM: wave = 64 rows x 32 W2-cols: 32 k-steps x {1 B-load, 2 ds_read,
//        2 MFMA}, B 6-deep, A 2-deep per ni.
//  EPI : +b2, LN2 (lane-local + shfl + stf), lrelu, layer3 vectorized,
//        shfl(32) + opart[64][8][3] (aliases As).
// ---------------------------------------------------------------------------
template<bool PREP>
__global__ __launch_bounds__(512, 2) void mlp_main(
  const float* __restrict__ points, const int* __restrict__ cats,
  const float* __restrict__ W1, const float* __restrict__ b1,
  const float* __restrict__ g1, const float* __restrict__ be1,
  const float* __restrict__ W2f, const float* __restrict__ b2,
  const float* __restrict__ g2, const float* __restrict__ be2,
  const float* __restrict__ W3, const float* __restrict__ b3,
  const unsigned short* __restrict__ W2s,
  float* __restrict__ out)
{
  __shared__ unsigned short As[64 * 1024 / 2 * 2];  // 64KB: frag (t,ni) at [(t*2+ni)*512]
  float* stf = (float*)As;                          // stats floats [0,1024); opart [1024,2560)

  const int tid  = (int)threadIdx.x;
  const int lane = tid & 63;
  const int w    = tid >> 6;            // wave 0..7
  const int pr   = lane & 31;
  const int kh   = lane >> 5;
  const size_t row0 = (size_t)blockIdx.x * 64;
  const int e = cats[row0 >> 13];
  const int wbase = w * 32;             // GEMM: wave's 32 W2-cols

  // ---------------- layer1 via 32x32x16 MFMA ----------------
  f32x16 a1[2][2];                      // [mi: col-frag][ni: row-frag]
  float al1[2], bt1[2];
  {
    const float* W1e = W1 + (size_t)e * 3 * NH;
    const float* b1e = b1 + (size_t)e * NH;
    short8 apf[2];                      // points as B-operand, rows ni*32+pr
    #pragma unroll
    for(int ni = 0; ni < 2; ni++){
      const float* pp = points + (row0 + ni * 32 + pr) * 3;
      union { short8 s; unsigned u[4]; } v;
      v.s = short8{0,0,0,0,0,0,0,0};
      if(kh == 0){ v.u[0] = pkbf(pp[0], pp[1]); v.u[1] = pkbf(pp[2], 1.0f); }
      apf[ni] = v.s;
    }
    #pragma unroll
    for(int mi = 0; mi < 2; mi++){
      int col = w * 64 + mi * 32 + pr;
      union { short8 s; unsigned u[4]; } bw;
      bw.s = short8{0,0,0,0,0,0,0,0};
      if(kh == 0){
        bw.u[0] = pkbf(W1e[col], W1e[NH + col]);
        bw.u[1] = pkbf(W1e[2 * NH + col], b1e[col]);
      }
      #pragma unroll
      for(int ni = 0; ni < 2; ni++){
        f32x16 z = {0.f,0.f,0.f,0.f,0.f,0.f,0.f,0.f,0.f,0.f,0.f,0.f,0.f,0.f,0.f,0.f};
        a1[mi][ni] = __builtin_amdgcn_mfma_f32_32x32x16_bf16(bw.s, apf[ni], z, 0, 0, 0);
      }
    }
    // LN1 stats: lane's values for row ni*32+pr (32 vals over wave's 64 cols)
    #pragma unroll
    for(int ni = 0; ni < 2; ni++){
      float s = 0.f, q = 0.f;
      #pragma unroll
      for(int mi = 0; mi < 2; mi++)
        #pragma unroll
        for(int r = 0; r < 16; r++){ float x = a1[mi][ni][r]; s += x; q = fmaf(x, x, q); }
      s += __shfl_xor(s, 32); q += __shfl_xor(q, 32);
      if(kh == 0){
        float2 sq; sq.x = s; sq.y = q;
        *(float2*)(&stf[(ni * 32 + pr) * 16 + w * 2]) = sq;
      }
    }
    __syncthreads();
    #pragma unroll
    for(int ni = 0; ni < 2; ni++){
      int row = ni * 32 + pr;
      float ssum = 0.f, qsum = 0.f;
      #pragma unroll
      for(int u = 0; u < 4; u++){
        f32x4 v = *(const f32x4*)&stf[row * 16 + u * 4];
        ssum += v[0] + v[2]; qsum += v[1] + v[3];
      }
      float mu = ssum * (1.f / NH);
      float rs = rsqrtf(fmaf(-mu, mu, qsum * (1.f / NH)) + HEPS);
      al1[ni] = rs; bt1[ni] = -mu * rs;
    }
    __syncthreads();   // stf fully read before As overwrite
  }
  // normalize + lrelu -> packed uint2 into frag-major As
  {
    const float* g1e  = g1  + (size_t)e * NH;
    const float* be1e = be1 + (size_t)e * NH;
    #pragma unroll
    for(int mi = 0; mi < 2; mi++){
      #pragma unroll
      for(int a = 0; a < 4; a++){
        int cb = w * 64 + mi * 32 + a * 8 + kh * 4;   // 4 feature cols
        f32x4 gg = *(const f32x4*)(g1e + cb);
        f32x4 ee = *(const f32x4*)(be1e + cb);
        int t = w * 4 + mi * 2 + (a >> 1);
        #pragma unroll
        for(int ni = 0; ni < 2; ni++){
          float xr[4];
          #pragma unroll
          for(int j = 0; j < 4; j++){
            float x = fmaf(a1[mi][ni][a * 4 + j], al1[ni], bt1[ni]);
            x = fmaf(x, gg[j], ee[j]);
            xr[j] = fmaxf(x, HSLOPE * x);
          }
          uint2 pk; pk.x = pkbf(xr[0], xr[1]); pk.y = pkbf(xr[2], xr[3]);
          int addr = ((t * 2 + ni) << 9) + ((a & 1) << 8) + pr * 8 + kh * 4;
          *(uint2*)(&As[addr]) = pk;
        }
      }
    }
  }

  // ---------------- B prefetch (W2 as A-operand, 1 frag/step), 6-deep ------
  auto loadB = [&](short8* dst, int t){
    if constexpr (PREP){
      const unsigned short* p = W2s + (((size_t)(e * 32 + t)) << 12)
                              + ((wbase + pr) << 4) + (kh << 3);
      *dst = *(const short8*)p;
    } else {
      const float* p = W2f + (((size_t)e * 512 + t * 16 + kh * 8) << 8)
                     + (wbase + pr);
      short8 v;
      #pragma unroll
      for(int kk = 0; kk < 8; kk++) v[kk] = (short)sbf(p[(size_t)kk << 8]);
      *dst = v;
    }
  };
  short8 bfr[6];
  #pragma unroll
  for(int d = 0; d < 6; d++) loadB(&bfr[d], d);

  __syncthreads();   // As complete

  // ---------------- GEMM: 32 barrier-free k-steps ----------------
  f32x16 acc[2];
  {
    f32x16 z = {0.f,0.f,0.f,0.f,0.f,0.f,0.f,0.f,0.f,0.f,0.f,0.f,0.f,0.f,0.f,0.f};
    acc[0] = z; acc[1] = z;
  }
  const int aoff = (kh << 8) + pr * 8;
  short8 af[2][2];   // [depth][ni]
  #pragma unroll
  for(int ni = 0; ni < 2; ni++){
    af[0][ni] = *(const short8*)&As[(ni << 9) + aoff];
    af[1][ni] = *(const short8*)&As[((2 + ni) << 9) + aoff];
  }

  #pragma unroll
  for(int t = 0; t < 32; t++){
    short8 a0 = af[t & 1][0], a1v = af[t & 1][1];
    if(t < 30){
      af[t & 1][0] = *(const short8*)&As[(((t + 2) * 2 + 0) << 9) + aoff];
      af[t & 1][1] = *(const short8*)&As[(((t + 2) * 2 + 1) << 9) + aoff];
    }
    acc[0] = __builtin_amdgcn_mfma_f32_32x32x16_bf16(bfr[t % 6], a0, acc[0], 0, 0, 0);
    acc[1] = __builtin_amdgcn_mfma_f32_32x32x16_bf16(bfr[t % 6], a1v, acc[1], 0, 0, 0);
    if(t < 26) loadB(&bfr[t % 6], t + 6);
  }

  __syncthreads();   // GEMM As reads done before stf2 aliases

  // ---------------- epilogue: +b2, LN2, lrelu, layer3 ----------------
  {
    const float* b2e = b2 + (size_t)e * 256;
    #pragma unroll
    for(int a = 0; a < 4; a++){
      int cb = wbase + a * 8 + kh * 4;
      f32x4 bb = *(const f32x4*)(b2e + cb);
      #pragma unroll
      for(int ni = 0; ni < 2; ni++)
        #pragma unroll
        for(int j = 0; j < 4; j++) acc[ni][a * 4 + j] += bb[j];
    }
    // LN2 stats
    float al2[2], bt2[2];
    #pragma unroll
    for(int ni = 0; ni < 2; ni++){
      float s = 0.f, q = 0.f;
      #pragma unroll
      for(int r = 0; r < 16; r++){ float x = acc[ni][r]; s += x; q = fmaf(x, x, q); }
      s += __shfl_xor(s, 32); q += __shfl_xor(q, 32);
      if(kh == 0){
        float2 sq; sq.x = s; sq.y = q;
        *(float2*)(&stf[(ni * 32 + pr) * 16 + w * 2]) = sq;
      }
    }
    __syncthreads();
    #pragma unroll
    for(int ni = 0; ni < 2; ni++){
      int row = ni * 32 + pr;
      float ssum = 0.f, qsum = 0.f;
      #pragma unroll
      for(int u = 0; u < 4; u++){
        f32x4 v = *(const f32x4*)&stf[row * 16 + u * 4];
        ssum += v[0] + v[2]; qsum += v[1] + v[3];
      }
      float mu = ssum * (1.f / 256.f);
      float rs = rsqrtf(fmaf(-mu, mu, qsum * (1.f / 256.f)) + HEPS);
      al2[ni] = rs; bt2[ni] = -mu * rs;
    }
    // normalize + lrelu + layer3 (vectorized)
    const float* g2e  = g2  + (size_t)e * 256;
    const float* be2e = be2 + (size_t)e * 256;
    const float* W3e  = W3 + (size_t)e * 256 * 3;
    float o[2][3];
    o[0][0]=0.f;o[0][1]=0.f;o[0][2]=0.f;o[1][0]=0.f;o[1][1]=0.f;o[1][2]=0.f;
    #pragma unroll
    for(int a = 0; a < 4; a++){
      int cb = wbase + a * 8 + kh * 4;
      f32x4 gg = *(const f32x4*)(g2e + cb);
      f32x4 ee = *(const f32x4*)(be2e + cb);
      float w3f[12];
      *(f32x4*)(w3f)     = *(const f32x4*)(W3e + cb * 3);
      *(f32x4*)(w3f + 4) = *(const f32x4*)(W3e + cb * 3 + 4);
      *(f32x4*)(w3f + 8) = *(const f32x4*)(W3e + cb * 3 + 8);
      #pragma unroll
      for(int ni = 0; ni < 2; ni++)
        #pragma unroll
        for(int j = 0; j < 4; j++){
          float x = fmaf(acc[ni][a * 4 + j], al2[ni], bt2[ni]);
          x = fmaf(x, gg[j], ee[j]);
          x = fmaxf(x, HSLOPE * x);
          o[ni][0] = fmaf(x, w3f[j * 3 + 0], o[ni][0]);
          o[ni][1] = fmaf(x, w3f[j * 3 + 1], o[ni][1]);
          o[ni][2] = fmaf(x, w3f[j * 3 + 2], o[ni][2]);
        }
    }
    #pragma unroll
    for(int ni = 0; ni < 2; ni++)
      #pragma unroll
      for(int c = 0; c < 3; c++){
        float v = o[ni][c];
        v += __shfl_xor(v, 32);
        o[ni][c] = v;
      }
    float* opart = stf + 1024;   // [64][8][3] floats at [1024,2560)
    if(kh == 0){
      #pragma unroll
      for(int ni = 0; ni < 2; ni++){
        opart[(ni * 32 + pr) * 24 + w * 3 + 0] = o[ni][0];
        opart[(ni * 32 + pr) * 24 + w * 3 + 1] = o[ni][1];
        opart[(ni * 32 + pr) * 24 + w * 3 + 2] = o[ni][2];
      }
    }
    __syncthreads();
    if(tid < 192){
      int rr = tid / 3, c = tid - rr * 3;
      float v = b3[e * 3 + c];
      #pragma unroll
      for(int ww = 0; ww < 8; ww++) v += opart[rr * 24 + ww * 3 + c];
      out[(row0 + rr) * 3 + c] = v;
    }
  }
}

extern "C" void kernel_launch(void* const* d_in, const int* in_sizes, int n_in,
                              void* d_out, int out_size, void* d_ws, size_t ws_size,
                              hipStream_t stream) {
  const float* points = (const float*)d_in[0];
  const int*   cats   = (const int*)d_in[1];
  const float* W1  = (const float*)d_in[2];
  const float* b1  = (const float*)d_in[3];
  const float* g1  = (const float*)d_in[4];
  const float* be1 = (const float*)d_in[5];
  const float* W2  = (const float*)d_in[6];
  const float* b2  = (const float*)d_in[7];
  const float* g2  = (const float*)d_in[8];
  const float* be2 = (const float*)d_in[9];
  const float* W3  = (const float*)d_in[10];
  const float* b3  = (const float*)d_in[11];
  float* out = (float*)d_out;

  const size_t W2IMG = (size_t)NE * 512 * 256 * 2;   // 2.62 MB bf16 image
  const int grid = NB * NN / 64;                     // 4096 blocks

  if (ws_size >= W2IMG) {
    unsigned short* wsW2 = (unsigned short*)d_ws;
    prep_w2<<<dim3((NE * 512 * 256) / 256), dim3(256), 0, stream>>>(W2, wsW2);
    mlp_main<true><<<dim3(grid), dim3(512), 0, stream>>>(
        points, cats, W1, b1, g1, be1, W2, b2, g2, be2, W3, b3, wsW2, out);
  } else {
    mlp_main<false><<<dim3(grid), dim3(512), 0, stream>>>(
        points, cats, W1, b1, g1, be1, W2, b2, g2, be2, W3, b3, nullptr, out);
  }
}

// Round 14
// 126.339 us; speedup vs baseline: 1.3058x; 1.3058x over previous
//
#include <hip/hip_runtime.h>
#include <hip/hip_bf16.h>
#include <stdint.h>
#include <stddef.h>

#define NB 32
#define NN 8192
#define NH 512
#define NE 10
#define HEPS 1e-5f
#define HSLOPE 0.2f

typedef short short8 __attribute__((ext_vector_type(8)));
typedef float f32x4 __attribute__((ext_vector_type(4)));
typedef float f32x16 __attribute__((ext_vector_type(16)));

static __device__ __forceinline__ unsigned short sbf(float a){
  __hip_bfloat16 t = __float2bfloat16(a);
  return *reinterpret_cast<unsigned short*>(&t);
}
static __device__ __forceinline__ unsigned pkbf(float a, float b){
  float2 f2; f2.x = a; f2.y = b;
  __hip_bfloat162 t = __float22bfloat162_rn(f2);
  return *reinterpret_cast<unsigned*>(&t);
}

// ---------------------------------------------------------------------------
// Prep: W2 [E][512][256] f32 -> bf16 image for 32x32x16 fragments (as R10).
// [e][t(32)][col(256)][kh(2)][kk(8)]: a wave's 32-col frag at k-step t is
// one coalesced 16B/lane load.
// ---------------------------------------------------------------------------
__global__ __launch_bounds__(256) void prep_w2(const float* __restrict__ W2,
                                               unsigned short* __restrict__ ws){
  int idx = blockIdx.x * 256 + threadIdx.x;
  int col = idx & 255;
  int k   = (idx >> 8) & 511;
  int e   = idx >> 17;
  int t = k >> 4, kh = (k >> 3) & 1, kk = k & 7;
  ws[(((size_t)(e * 32 + t)) << 12) + (col << 4) + (kh << 3) + kk] = sbf(W2[idx]);
}

// ---------------------------------------------------------------------------
// Main (R14): R13 with two fixes:
//  (1) As = exactly 64KB (R13 accidentally declared 128KB -> 1 block/CU);
//      now 2 blocks/CU x 8 waves = 16 waves/CU with HALVED B-load count.
//  (2) stats stride 20 floats (was 16): octet banks pr*20%32 all distinct ->
//      conflict-free stats reads/writes (R11/R13's 1.2e7 conflicts).
// Structure: BM=64, 512 thr, wave = 64 rows x 32 W2-cols; 32x32x16 swapped
// pipeline; B 6-deep from L2 prep image; A 2-deep x 2ni from LDS.
// ---------------------------------------------------------------------------
template<bool PREP>
__global__ __launch_bounds__(512, 2) void mlp_main(
  const float* __restrict__ points, const int* __restrict__ cats,
  const float* __restrict__ W1, const float* __restrict__ b1,
  const float* __restrict__ g1, const float* __restrict__ be1,
  const float* __restrict__ W2f, const float* __restrict__ b2,
  const float* __restrict__ g2, const float* __restrict__ be2,
  const float* __restrict__ W3, const float* __restrict__ b3,
  const unsigned short* __restrict__ W2s,
  float* __restrict__ out)
{
  __shared__ unsigned short As[64 * 512];   // 64KB: frag (t,ni) at [(t*2+ni)*512]
  float* stf = (float*)As;                  // stats [row*20 + w*2], rows<64 -> [0,1280)
                                            // opart at [1280, 1280+64*24)

  const int tid  = (int)threadIdx.x;
  const int lane = tid & 63;
  const int w    = tid >> 6;            // wave 0..7
  const int pr   = lane & 31;
  const int kh   = lane >> 5;
  const size_t row0 = (size_t)blockIdx.x * 64;
  const int e = cats[row0 >> 13];
  const int wbase = w * 32;             // GEMM: wave's 32 W2-cols

  // ---------------- layer1 via 32x32x16 MFMA ----------------
  f32x16 a1[2][2];                      // [mi: col-frag][ni: row-frag]
  float al1[2], bt1[2];
  {
    const float* W1e = W1 + (size_t)e * 3 * NH;
    const float* b1e = b1 + (size_t)e * NH;
    short8 apf[2];                      // points as B-operand, rows ni*32+pr
    #pragma unroll
    for(int ni = 0; ni < 2; ni++){
      const float* pp = points + (row0 + ni * 32 + pr) * 3;
      union { short8 s; unsigned u[4]; } v;
      v.s = short8{0,0,0,0,0,0,0,0};
      if(kh == 0){ v.u[0] = pkbf(pp[0], pp[1]); v.u[1] = pkbf(pp[2], 1.0f); }
      apf[ni] = v.s;
    }
    #pragma unroll
    for(int mi = 0; mi < 2; mi++){
      int col = w * 64 + mi * 32 + pr;
      union { short8 s; unsigned u[4]; } bw;
      bw.s = short8{0,0,0,0,0,0,0,0};
      if(kh == 0){
        bw.u[0] = pkbf(W1e[col], W1e[NH + col]);
        bw.u[1] = pkbf(W1e[2 * NH + col], b1e[col]);
      }
      #pragma unroll
      for(int ni = 0; ni < 2; ni++){
        f32x16 z = {0.f,0.f,0.f,0.f,0.f,0.f,0.f,0.f,0.f,0.f,0.f,0.f,0.f,0.f,0.f,0.f};
        a1[mi][ni] = __builtin_amdgcn_mfma_f32_32x32x16_bf16(bw.s, apf[ni], z, 0, 0, 0);
      }
    }
    // LN1 stats: lane's values for row ni*32+pr (32 vals over wave's 64 cols)
    #pragma unroll
    for(int ni = 0; ni < 2; ni++){
      float s = 0.f, q = 0.f;
      #pragma unroll
      for(int mi = 0; mi < 2; mi++)
        #pragma unroll
        for(int r = 0; r < 16; r++){ float x = a1[mi][ni][r]; s += x; q = fmaf(x, x, q); }
      s += __shfl_xor(s, 32); q += __shfl_xor(q, 32);
      if(kh == 0){
        float2 sq; sq.x = s; sq.y = q;
        *(float2*)(&stf[(ni * 32 + pr) * 20 + w * 2]) = sq;
      }
    }
    __syncthreads();
    #pragma unroll
    for(int ni = 0; ni < 2; ni++){
      int row = ni * 32 + pr;
      float ssum = 0.f, qsum = 0.f;
      #pragma unroll
      for(int u = 0; u < 4; u++){
        f32x4 v = *(const f32x4*)&stf[row * 20 + u * 4];
        ssum += v[0] + v[2]; qsum += v[1] + v[3];
      }
      float mu = ssum * (1.f / NH);
      float rs = rsqrtf(fmaf(-mu, mu, qsum * (1.f / NH)) + HEPS);
      al1[ni] = rs; bt1[ni] = -mu * rs;
    }
    __syncthreads();   // stf fully read before As overwrite
  }
  // normalize + lrelu -> packed uint2 into frag-major As
  {
    const float* g1e  = g1  + (size_t)e * NH;
    const float* be1e = be1 + (size_t)e * NH;
    #pragma unroll
    for(int mi = 0; mi < 2; mi++){
      #pragma unroll
      for(int a = 0; a < 4; a++){
        int cb = w * 64 + mi * 32 + a * 8 + kh * 4;   // 4 feature cols
        f32x4 gg = *(const f32x4*)(g1e + cb);
        f32x4 ee = *(const f32x4*)(be1e + cb);
        int t = w * 4 + mi * 2 + (a >> 1);
        #pragma unroll
        for(int ni = 0; ni < 2; ni++){
          float xr[4];
          #pragma unroll
          for(int j = 0; j < 4; j++){
            float x = fmaf(a1[mi][ni][a * 4 + j], al1[ni], bt1[ni]);
            x = fmaf(x, gg[j], ee[j]);
            xr[j] = fmaxf(x, HSLOPE * x);
          }
          uint2 pk; pk.x = pkbf(xr[0], xr[1]); pk.y = pkbf(xr[2], xr[3]);
          int addr = ((t * 2 + ni) << 9) + ((a & 1) << 8) + pr * 8 + kh * 4;
          *(uint2*)(&As[addr]) = pk;
        }
      }
    }
  }

  // ---------------- B prefetch (W2 as A-operand, 1 frag/step), 6-deep ------
  auto loadB = [&](short8* dst, int t){
    if constexpr (PREP){
      const unsigned short* p = W2s + (((size_t)(e * 32 + t)) << 12)
                              + ((wbase + pr) << 4) + (kh << 3);
      *dst = *(const short8*)p;
    } else {
      const float* p = W2f + (((size_t)e * 512 + t * 16 + kh * 8) << 8)
                     + (wbase + pr);
      short8 v;
      #pragma unroll
      for(int kk = 0; kk < 8; kk++) v[kk] = (short)sbf(p[(size_t)kk << 8]);
      *dst = v;
    }
  };
  short8 bfr[6];
  #pragma unroll
  for(int d = 0; d < 6; d++) loadB(&bfr[d], d);

  __syncthreads();   // As complete

  // ---------------- GEMM: 32 barrier-free k-steps ----------------
  f32x16 acc[2];
  {
    f32x16 z = {0.f,0.f,0.f,0.f,0.f,0.f,0.f,0.f,0.f,0.f,0.f,0.f,0.f,0.f,0.f,0.f};
    acc[0] = z; acc[1] = z;
  }
  const int aoff = (kh << 8) + pr * 8;
  short8 af[2][2];   // [depth][ni]
  #pragma unroll
  for(int ni = 0; ni < 2; ni++){
    af[0][ni] = *(const short8*)&As[(ni << 9) + aoff];
    af[1][ni] = *(const short8*)&As[((2 + ni) << 9) + aoff];
  }

  #pragma unroll
  for(int t = 0; t < 32; t++){
    short8 a0 = af[t & 1][0], a1v = af[t & 1][1];
    if(t < 30){
      af[t & 1][0] = *(const short8*)&As[(((t + 2) * 2 + 0) << 9) + aoff];
      af[t & 1][1] = *(const short8*)&As[(((t + 2) * 2 + 1) << 9) + aoff];
    }
    acc[0] = __builtin_amdgcn_mfma_f32_32x32x16_bf16(bfr[t % 6], a0, acc[0], 0, 0, 0);
    acc[1] = __builtin_amdgcn_mfma_f32_32x32x16_bf16(bfr[t % 6], a1v, acc[1], 0, 0, 0);
    if(t < 26) loadB(&bfr[t % 6], t + 6);
  }

  __syncthreads();   // GEMM As reads done before stf2 aliases

  // ---------------- epilogue: +b2, LN2, lrelu, layer3 ----------------
  {
    const float* b2e = b2 + (size_t)e * 256;
    #pragma unroll
    for(int a = 0; a < 4; a++){
      int cb = wbase + a * 8 + kh * 4;
      f32x4 bb = *(const f32x4*)(b2e + cb);
      #pragma unroll
      for(int ni = 0; ni < 2; ni++)
        #pragma unroll
        for(int j = 0; j < 4; j++) acc[ni][a * 4 + j] += bb[j];
    }
    // LN2 stats
    float al2[2], bt2[2];
    #pragma unroll
    for(int ni = 0; ni < 2; ni++){
      float s = 0.f, q = 0.f;
      #pragma unroll
      for(int r = 0; r < 16; r++){ float x = acc[ni][r]; s += x; q = fmaf(x, x, q); }
      s += __shfl_xor(s, 32); q += __shfl_xor(q, 32);
      if(kh == 0){
        float2 sq; sq.x = s; sq.y = q;
        *(float2*)(&stf[(ni * 32 + pr) * 20 + w * 2]) = sq;
      }
    }
    __syncthreads();
    #pragma unroll
    for(int ni = 0; ni < 2; ni++){
      int row = ni * 32 + pr;
      float ssum = 0.f, qsum = 0.f;
      #pragma unroll
      for(int u = 0; u < 4; u++){
        f32x4 v = *(const f32x4*)&stf[row * 20 + u * 4];
        ssum += v[0] + v[2]; qsum += v[1] + v[3];
      }
      float mu = ssum * (1.f / 256.f);
      float rs = rsqrtf(fmaf(-mu, mu, qsum * (1.f / 256.f)) + HEPS);
      al2[ni] = rs; bt2[ni] = -mu * rs;
    }
    // normalize + lrelu + layer3 (vectorized)
    const float* g2e  = g2  + (size_t)e * 256;
    const float* be2e = be2 + (size_t)e * 256;
    const float* W3e  = W3 + (size_t)e * 256 * 3;
    float o[2][3];
    o[0][0]=0.f;o[0][1]=0.f;o[0][2]=0.f;o[1][0]=0.f;o[1][1]=0.f;o[1][2]=0.f;
    #pragma unroll
    for(int a = 0; a < 4; a++){
      int cb = wbase + a * 8 + kh * 4;
      f32x4 gg = *(const f32x4*)(g2e + cb);
      f32x4 ee = *(const f32x4*)(be2e + cb);
      float w3f[12];
      *(f32x4*)(w3f)     = *(const f32x4*)(W3e + cb * 3);
      *(f32x4*)(w3f + 4) = *(const f32x4*)(W3e + cb * 3 + 4);
      *(f32x4*)(w3f + 8) = *(const f32x4*)(W3e + cb * 3 + 8);
      #pragma unroll
      for(int ni = 0; ni < 2; ni++)
        #pragma unroll
        for(int j = 0; j < 4; j++){
          float x = fmaf(acc[ni][a * 4 + j], al2[ni], bt2[ni]);
          x = fmaf(x, gg[j], ee[j]);
          x = fmaxf(x, HSLOPE * x);
          o[ni][0] = fmaf(x, w3f[j * 3 + 0], o[ni][0]);
          o[ni][1] = fmaf(x, w3f[j * 3 + 1], o[ni][1]);
          o[ni][2] = fmaf(x, w3f[j * 3 + 2], o[ni][2]);
        }
    }
    #pragma unroll
    for(int ni = 0; ni < 2; ni++)
      #pragma unroll
      for(int c = 0; c < 3; c++){
        float v = o[ni][c];
        v += __shfl_xor(v, 32);
        o[ni][c] = v;
      }
    float* opart = stf + 1280;   // [64][8][3] floats
    if(kh == 0){
      #pragma unroll
      for(int ni = 0; ni < 2; ni++){
        opart[(ni * 32 + pr) * 24 + w * 3 + 0] = o[ni][0];
        opart[(ni * 32 + pr) * 24 + w * 3 + 1] = o[ni][1];
        opart[(ni * 32 + pr) * 24 + w * 3 + 2] = o[ni][2];
      }
    }
    __syncthreads();
    if(tid < 192){
      int rr = tid / 3, c = tid - rr * 3;
      float v = b3[e * 3 + c];
      #pragma unroll
      for(int ww = 0; ww < 8; ww++) v += opart[rr * 24 + ww * 3 + c];
      out[(row0 + rr) * 3 + c] = v;
    }
  }
}

extern "C" void kernel_launch(void* const* d_in, const int* in_sizes, int n_in,
                              void* d_out, int out_size, void* d_ws, size_t ws_size,
                              hipStream_t stream) {
  const float* points = (const float*)d_in[0];
  const int*   cats   = (const int*)d_in[1];
  const float* W1  = (const float*)d_in[2];
  const float* b1  = (const float*)d_in[3];
  const float* g1  = (const float*)d_in[4];
  const float* be1 = (const float*)d_in[5];
  const float* W2  = (const float*)d_in[6];
  const float* b2  = (const float*)d_in[7];
  const float* g2  = (const float*)d_in[8];
  const float* be2 = (const float*)d_in[9];
  const float* W3  = (const float*)d_in[10];
  const float* b3  = (const float*)d_in[11];
  float* out = (float*)d_out;

  const size_t W2IMG = (size_t)NE * 512 * 256 * 2;   // 2.62 MB bf16 image
  const int grid = NB * NN / 64;                     // 4096 blocks

  if (ws_size >= W2IMG) {
    unsigned short* wsW2 = (unsigned short*)d_ws;
    prep_w2<<<dim3((NE * 512 * 256) / 256), dim3(256), 0, stream>>>(W2, wsW2);
    mlp_main<true><<<dim3(grid), dim3(512), 0, stream>>>(
        points, cats, W1, b1, g1, be1, W2, b2, g2, be2, W3, b3, wsW2, out);
  } else {
    mlp_main<false><<<dim3(grid), dim3(512), 0, stream>>>(
        points, cats, W1, b1, g1, be1, W2, b2, g2, be2, W3, b3, nullptr, out);
  }
}

// Round 15
// 124.877 us; speedup vs baseline: 1.3211x; 1.0117x over previous
//
#include <hip/hip_runtime.h>
#include <hip/hip_bf16.h>
#include <stdint.h>
#include <stddef.h>

#define NB 32
#define NN 8192
#define NH 512
#define NE 10
#define HEPS 1e-5f
#define HSLOPE 0.2f

typedef short short8 __attribute__((ext_vector_type(8)));
typedef float f32x4 __attribute__((ext_vector_type(4)));
typedef float f32x16 __attribute__((ext_vector_type(16)));

static __device__ __forceinline__ unsigned short sbf(float a){
  __hip_bfloat16 t = __float2bfloat16(a);
  return *reinterpret_cast<unsigned short*>(&t);
}
static __device__ __forceinline__ unsigned pkbf(float a, float b){
  float2 f2; f2.x = a; f2.y = b;
  __hip_bfloat162 t = __float22bfloat162_rn(f2);
  return *reinterpret_cast<unsigned*>(&t);
}

// ---------------------------------------------------------------------------
// Prep: W2 [E][512][256] f32 -> bf16 image for 32x32x16 fragments (as R10).
// [e][t(32)][col(256)][kh(2)][kk(8)]: a wave's 32-col frag at k-step t is
// one coalesced 16B/lane load.
// ---------------------------------------------------------------------------
__global__ __launch_bounds__(256) void prep_w2(const float* __restrict__ W2,
                                               unsigned short* __restrict__ ws){
  int idx = blockIdx.x * 256 + threadIdx.x;
  int col = idx & 255;
  int k   = (idx >> 8) & 511;
  int e   = idx >> 17;
  int t = k >> 4, kh = (k >> 3) & 1, kk = k & 7;
  ws[(((size_t)(e * 32 + t)) << 12) + (col << 4) + (kh << 3) + kk] = sbf(W2[idx]);
}

// ---------------------------------------------------------------------------
// Main (R15): R14 structure (BM=64, 512 thr, 8 waves, 64KB frag-major As,
// 2 blocks/CU) with stall-cutting changes:
//  (1) stats (stq, 5KB) and opart (6KB) are SEPARATE LDS buffers -> the two
//      As-alias guard barriers and the post-GEMM barrier are removed
//      (6 -> 4 barriers/block). Total LDS 75KB, still 2 blocks/CU.
//  (2) s_setprio(1) around the GEMM MFMA pair (T5: co-resident blocks are
//      at different phases -> scheduler can favor the MFMA wave).
//  (3) A-prefetch depth 3 (VGPR headroom: 64 used vs 128 cap).
// ---------------------------------------------------------------------------
template<bool PREP>
__global__ __launch_bounds__(512, 2) void mlp_main(
  const float* __restrict__ points, const int* __restrict__ cats,
  const float* __restrict__ W1, const float* __restrict__ b1,
  const float* __restrict__ g1, const float* __restrict__ be1,
  const float* __restrict__ W2f, const float* __restrict__ b2,
  const float* __restrict__ g2, const float* __restrict__ be2,
  const float* __restrict__ W3, const float* __restrict__ b3,
  const unsigned short* __restrict__ W2s,
  float* __restrict__ out)
{
  __shared__ unsigned short As[64 * 512];   // 64KB: frag (t,ni) at [(t*2+ni)*512]
  __shared__ float stq[64 * 20];            // 5KB stats: [row*20 + w*2] (stride 20: conflict-free)
  __shared__ float opart[64 * 24];          // 6KB layer3 partials

  const int tid  = (int)threadIdx.x;
  const int lane = tid & 63;
  const int w    = tid >> 6;            // wave 0..7
  const int pr   = lane & 31;
  const int kh   = lane >> 5;
  const size_t row0 = (size_t)blockIdx.x * 64;
  const int e = cats[row0 >> 13];
  const int wbase = w * 32;             // GEMM: wave's 32 W2-cols

  // ---------------- layer1 via 32x32x16 MFMA ----------------
  f32x16 a1[2][2];                      // [mi: col-frag][ni: row-frag]
  float al1[2], bt1[2];
  {
    const float* W1e = W1 + (size_t)e * 3 * NH;
    const float* b1e = b1 + (size_t)e * NH;
    short8 apf[2];                      // points as B-operand, rows ni*32+pr
    #pragma unroll
    for(int ni = 0; ni < 2; ni++){
      const float* pp = points + (row0 + ni * 32 + pr) * 3;
      union { short8 s; unsigned u[4]; } v;
      v.s = short8{0,0,0,0,0,0,0,0};
      if(kh == 0){ v.u[0] = pkbf(pp[0], pp[1]); v.u[1] = pkbf(pp[2], 1.0f); }
      apf[ni] = v.s;
    }
    #pragma unroll
    for(int mi = 0; mi < 2; mi++){
      int col = w * 64 + mi * 32 + pr;
      union { short8 s; unsigned u[4]; } bw;
      bw.s = short8{0,0,0,0,0,0,0,0};
      if(kh == 0){
        bw.u[0] = pkbf(W1e[col], W1e[NH + col]);
        bw.u[1] = pkbf(W1e[2 * NH + col], b1e[col]);
      }
      #pragma unroll
      for(int ni = 0; ni < 2; ni++){
        f32x16 z = {0.f,0.f,0.f,0.f,0.f,0.f,0.f,0.f,0.f,0.f,0.f,0.f,0.f,0.f,0.f,0.f};
        a1[mi][ni] = __builtin_amdgcn_mfma_f32_32x32x16_bf16(bw.s, apf[ni], z, 0, 0, 0);
      }
    }
    // LN1 stats: lane's values for row ni*32+pr (32 vals over wave's 64 cols)
    #pragma unroll
    for(int ni = 0; ni < 2; ni++){
      float s = 0.f, q = 0.f;
      #pragma unroll
      for(int mi = 0; mi < 2; mi++)
        #pragma unroll
        for(int r = 0; r < 16; r++){ float x = a1[mi][ni][r]; s += x; q = fmaf(x, x, q); }
      s += __shfl_xor(s, 32); q += __shfl_xor(q, 32);
      if(kh == 0){
        float2 sq; sq.x = s; sq.y = q;
        *(float2*)(&stq[(ni * 32 + pr) * 20 + w * 2]) = sq;
      }
    }
    __syncthreads();                    // (1) all LN1 stats written
    #pragma unroll
    for(int ni = 0; ni < 2; ni++){
      int row = ni * 32 + pr;
      float ssum = 0.f, qsum = 0.f;
      #pragma unroll
      for(int u = 0; u < 4; u++){
        f32x4 v = *(const f32x4*)&stq[row * 20 + u * 4];
        ssum += v[0] + v[2]; qsum += v[1] + v[3];
      }
      float mu = ssum * (1.f / NH);
      float rs = rsqrtf(fmaf(-mu, mu, qsum * (1.f / NH)) + HEPS);
      al1[ni] = rs; bt1[ni] = -mu * rs;
    }
    // no barrier: As is disjoint from stq
  }
  // normalize + lrelu -> packed uint2 into frag-major As
  {
    const float* g1e  = g1  + (size_t)e * NH;
    const float* be1e = be1 + (size_t)e * NH;
    #pragma unroll
    for(int mi = 0; mi < 2; mi++){
      #pragma unroll
      for(int a = 0; a < 4; a++){
        int cb = w * 64 + mi * 32 + a * 8 + kh * 4;   // 4 feature cols
        f32x4 gg = *(const f32x4*)(g1e + cb);
        f32x4 ee = *(const f32x4*)(be1e + cb);
        int t = w * 4 + mi * 2 + (a >> 1);
        #pragma unroll
        for(int ni = 0; ni < 2; ni++){
          float xr[4];
          #pragma unroll
          for(int j = 0; j < 4; j++){
            float x = fmaf(a1[mi][ni][a * 4 + j], al1[ni], bt1[ni]);
            x = fmaf(x, gg[j], ee[j]);
            xr[j] = fmaxf(x, HSLOPE * x);
          }
          uint2 pk; pk.x = pkbf(xr[0], xr[1]); pk.y = pkbf(xr[2], xr[3]);
          int addr = ((t * 2 + ni) << 9) + ((a & 1) << 8) + pr * 8 + kh * 4;
          *(uint2*)(&As[addr]) = pk;
        }
      }
    }
  }

  // ---------------- B prefetch (W2 as A-operand, 1 frag/step), 6-deep ------
  auto loadB = [&](short8* dst, int t){
    if constexpr (PREP){
      const unsigned short* p = W2s + (((size_t)(e * 32 + t)) << 12)
                              + ((wbase + pr) << 4) + (kh << 3);
      *dst = *(const short8*)p;
    } else {
      const float* p = W2f + (((size_t)e * 512 + t * 16 + kh * 8) << 8)
                     + (wbase + pr);
      short8 v;
      #pragma unroll
      for(int kk = 0; kk < 8; kk++) v[kk] = (short)sbf(p[(size_t)kk << 8]);
      *dst = v;
    }
  };
  short8 bfr[6];
  #pragma unroll
  for(int d = 0; d < 6; d++) loadB(&bfr[d], d);

  __syncthreads();                      // (2) As complete

  // ---------------- GEMM: 32 barrier-free k-steps ----------------
  f32x16 acc[2];
  {
    f32x16 z = {0.f,0.f,0.f,0.f,0.f,0.f,0.f,0.f,0.f,0.f,0.f,0.f,0.f,0.f,0.f,0.f};
    acc[0] = z; acc[1] = z;
  }
  const int aoff = (kh << 8) + pr * 8;
  short8 af[3][2];   // depth-3 A prefetch
  #pragma unroll
  for(int d = 0; d < 3; d++){
    af[d][0] = *(const short8*)&As[((d * 2 + 0) << 9) + aoff];
    af[d][1] = *(const short8*)&As[((d * 2 + 1) << 9) + aoff];
  }

  #pragma unroll
  for(int t = 0; t < 32; t++){
    short8 a0 = af[t % 3][0], a1v = af[t % 3][1];
    if(t < 29){
      af[t % 3][0] = *(const short8*)&As[(((t + 3) * 2 + 0) << 9) + aoff];
      af[t % 3][1] = *(const short8*)&As[(((t + 3) * 2 + 1) << 9) + aoff];
    }
    __builtin_amdgcn_s_setprio(1);
    acc[0] = __builtin_amdgcn_mfma_f32_32x32x16_bf16(bfr[t % 6], a0, acc[0], 0, 0, 0);
    acc[1] = __builtin_amdgcn_mfma_f32_32x32x16_bf16(bfr[t % 6], a1v, acc[1], 0, 0, 0);
    __builtin_amdgcn_s_setprio(0);
    if(t < 26) loadB(&bfr[t % 6], t + 6);
  }
  // no barrier: epilogue touches only stq/opart/regs, never As

  // ---------------- epilogue: +b2, LN2, lrelu, layer3 ----------------
  {
    const float* b2e = b2 + (size_t)e * 256;
    #pragma unroll
    for(int a = 0; a < 4; a++){
      int cb = wbase + a * 8 + kh * 4;
      f32x4 bb = *(const f32x4*)(b2e + cb);
      #pragma unroll
      for(int ni = 0; ni < 2; ni++)
        #pragma unroll
        for(int j = 0; j < 4; j++) acc[ni][a * 4 + j] += bb[j];
    }
    // LN2 stats
    float al2[2], bt2[2];
    #pragma unroll
    for(int ni = 0; ni < 2; ni++){
      float s = 0.f, q = 0.f;
      #pragma unroll
      for(int r = 0; r < 16; r++){ float x = acc[ni][r]; s += x; q = fmaf(x, x, q); }
      s += __shfl_xor(s, 32); q += __shfl_xor(q, 32);
      if(kh == 0){
        float2 sq; sq.x = s; sq.y = q;
        *(float2*)(&stq[(ni * 32 + pr) * 20 + w * 2]) = sq;
      }
    }
    __syncthreads();                    // (3) all LN2 stats written
    #pragma unroll
    for(int ni = 0; ni < 2; ni++){
      int row = ni * 32 + pr;
      float ssum = 0.f, qsum = 0.f;
      #pragma unroll
      for(int u = 0; u < 4; u++){
        f32x4 v = *(const f32x4*)&stq[row * 20 + u * 4];
        ssum += v[0] + v[2]; qsum += v[1] + v[3];
      }
      float mu = ssum * (1.f / 256.f);
      float rs = rsqrtf(fmaf(-mu, mu, qsum * (1.f / 256.f)) + HEPS);
      al2[ni] = rs; bt2[ni] = -mu * rs;
    }
    // normalize + lrelu + layer3 (vectorized)
    const float* g2e  = g2  + (size_t)e * 256;
    const float* be2e = be2 + (size_t)e * 256;
    const float* W3e  = W3 + (size_t)e * 256 * 3;
    float o[2][3];
    o[0][0]=0.f;o[0][1]=0.f;o[0][2]=0.f;o[1][0]=0.f;o[1][1]=0.f;o[1][2]=0.f;
    #pragma unroll
    for(int a = 0; a < 4; a++){
      int cb = wbase + a * 8 + kh * 4;
      f32x4 gg = *(const f32x4*)(g2e + cb);
      f32x4 ee = *(const f32x4*)(be2e + cb);
      float w3f[12];
      *(f32x4*)(w3f)     = *(const f32x4*)(W3e + cb * 3);
      *(f32x4*)(w3f + 4) = *(const f32x4*)(W3e + cb * 3 + 4);
      *(f32x4*)(w3f + 8) = *(const f32x4*)(W3e + cb * 3 + 8);
      #pragma unroll
      for(int ni = 0; ni < 2; ni++)
        #pragma unroll
        for(int j = 0; j < 4; j++){
          float x = fmaf(acc[ni][a * 4 + j], al2[ni], bt2[ni]);
          x = fmaf(x, gg[j], ee[j]);
          x = fmaxf(x, HSLOPE * x);
          o[ni][0] = fmaf(x, w3f[j * 3 + 0], o[ni][0]);
          o[ni][1] = fmaf(x, w3f[j * 3 + 1], o[ni][1]);
          o[ni][2] = fmaf(x, w3f[j * 3 + 2], o[ni][2]);
        }
    }
    #pragma unroll
    for(int ni = 0; ni < 2; ni++)
      #pragma unroll
      for(int c = 0; c < 3; c++){
        float v = o[ni][c];
        v += __shfl_xor(v, 32);
        o[ni][c] = v;
      }
    if(kh == 0){
      #pragma unroll
      for(int ni = 0; ni < 2; ni++){
        opart[(ni * 32 + pr) * 24 + w * 3 + 0] = o[ni][0];
        opart[(ni * 32 + pr) * 24 + w * 3 + 1] = o[ni][1];
        opart[(ni * 32 + pr) * 24 + w * 3 + 2] = o[ni][2];
      }
    }
    __syncthreads();                    // (4) opart complete
    if(tid < 192){
      int rr = tid / 3, c = tid - rr * 3;
      float v = b3[e * 3 + c];
      #pragma unroll
      for(int ww = 0; ww < 8; ww++) v += opart[rr * 24 + ww * 3 + c];
      out[(row0 + rr) * 3 + c] = v;
    }
  }
}

extern "C" void kernel_launch(void* const* d_in, const int* in_sizes, int n_in,
                              void* d_out, int out_size, void* d_ws, size_t ws_size,
                              hipStream_t stream) {
  const float* points = (const float*)d_in[0];
  const int*   cats   = (const int*)d_in[1];
  const float* W1  = (const float*)d_in[2];
  const float* b1  = (const float*)d_in[3];
  const float* g1  = (const float*)d_in[4];
  const float* be1 = (const float*)d_in[5];
  const float* W2  = (const float*)d_in[6];
  const float* b2  = (const float*)d_in[7];
  const float* g2  = (const float*)d_in[8];
  const float* be2 = (const float*)d_in[9];
  const float* W3  = (const float*)d_in[10];
  const float* b3  = (const float*)d_in[11];
  float* out = (float*)d_out;

  const size_t W2IMG = (size_t)NE * 512 * 256 * 2;   // 2.62 MB bf16 image
  const int grid = NB * NN / 64;                     // 4096 blocks

  if (ws_size >= W2IMG) {
    unsigned short* wsW2 = (unsigned short*)d_ws;
    prep_w2<<<dim3((NE * 512 * 256) / 256), dim3(256), 0, stream>>>(W2, wsW2);
    mlp_main<true><<<dim3(grid), dim3(512), 0, stream>>>(
        points, cats, W1, b1, g1, be1, W2, b2, g2, be2, W3, b3, wsW2, out);
  } else {
    mlp_main<false><<<dim3(grid), dim3(512), 0, stream>>>(
        points, cats, W1, b1, g1, be1, W2, b2, g2, be2, W3, b3, nullptr, out);
  }
}